// Round 7
// baseline (186.482 us; speedup 1.0000x reference)
//
#include <hip/hip_runtime.h>
#include <hip/hip_bf16.h>

// LDConv (deformable sampling + (N,1) conv + BN + SiLU) for MI355X.
//
// Round-20: ABLATION-BY-DECOMPOSITION. Five mechanism theories (latency
// reorder R14/R17, scatter restructure R16, L2-BW R18, barrier drain R19)
// all neutral: dur pinned 109-120us, MfmaUtil 16.5, VALU 26, occ 33.
// Stop theorizing about the monolith; split phase 2 into its two ops as
// separate dispatches so the rocprof table attributes the 73us — and each
// piece gets its natural structure:
//  - k_gather: wave-private barrier-free bilinear combine. Gathers stay
//    coalesced (4x256B segs, proven); COMB bit-identical; 16x16 transpose
//    of 16B chunks through wave-private LDS (lgkmcnt-ordered, NO barrier);
//    stores x_off in B-FRAGMENT-READY layout: per (16px,kc) chunk the
//    wave's frags are one contiguous 1KB -> k_gemm needs no LDS at all.
//  - k_gemm: a real GEMM (256oc x 51200px x 1152K = 30.2 GFLOP, a 12us op
//    at peak). Zero LDS, zero barriers: wave owns 16px x 256oc, acc 64
//    VGPR; per chunk 1 coalesced B-load + 16 wf frags + 16 MFMA (of-groups
//    of 4 fenced to cap liveness ~100 VGPR). 3200 independent waves.
//  - k_offconv: R13 standalone (proven 36us), desc via global again.
//  - Cost: x_off = 118MB write + read (L3-resident). Insurance: ws_size
//    checked; falls back to proven R15 fused path (114.6us) if too small.

typedef __attribute__((ext_vector_type(8))) short bf16x8;
typedef __attribute__((ext_vector_type(4))) float f32x4;
typedef __attribute__((ext_vector_type(2))) float f32x2;
typedef __attribute__((ext_vector_type(4))) unsigned int u32x4;

#define NHW 6400
#define NPIX 80

__device__ __forceinline__ unsigned short f2bf(float f){
  __hip_bfloat16 h = __float2bfloat16(f);
  unsigned short u; __builtin_memcpy(&u, &h, 2); return u;
}
__device__ __forceinline__ f32x2 bfp2f(unsigned int u){
  union { unsigned int i; float f; } a, b;
  a.i = u << 16; b.i = u & 0xffff0000u;
  f32x2 r; r.x = a.f; r.y = b.f; return r;
}
__device__ __forceinline__ unsigned pk_bf16(float a, float b){
  unsigned r;
  asm("v_cvt_pk_bf16_f32 %0, %1, %2" : "=v"(r) : "v"(a), "v"(b));
  return r;
}
__device__ __forceinline__ void splitbf(float v, unsigned short& hi, unsigned short& lo){
  hi = f2bf(v);
  union { unsigned int i; float f; } h; h.i = (unsigned)hi << 16;
  lo = f2bf(v - h.f);
}
__device__ __forceinline__ float f16u2f(unsigned int u){
  unsigned short s = (unsigned short)u; _Float16 h;
  __builtin_memcpy(&h, &s, 2); return (float)h;
}
__device__ __forceinline__ unsigned short f2f16u(float f){
  _Float16 h = (_Float16)f; unsigned short s;
  __builtin_memcpy(&s, &h, 2); return s;
}
__device__ __forceinline__ float fast_silu(float v){
  float e, r;
  asm("v_exp_f32 %0, %1" : "=v"(e) : "v"(v * -1.44269504088896f)); // exp(-v)
  asm("v_rcp_f32 %0, %1" : "=v"(r) : "v"(1.0f + e));
  return v * r;
}

// ---------------- merged: transpose (blk<800) + weight prep ----------------
__global__ __launch_bounds__(256) void k_pre(const float* __restrict__ x,
                                             const float* __restrict__ w_conv,
                                             const float* __restrict__ w_pconv,
                                             const float* __restrict__ gamma,
                                             const float* __restrict__ beta,
                                             const float* __restrict__ mean,
                                             const float* __restrict__ var,
                                             unsigned short* __restrict__ xt,
                                             unsigned short* __restrict__ xtl,
                                             uint4* __restrict__ wf,
                                             uint4* __restrict__ wpfH,
                                             uint4* __restrict__ wpfL,
                                             float* __restrict__ shift){
  __shared__ unsigned short tileH[64 * 132];
  __shared__ unsigned short tileL[64 * 132];
  int blk = blockIdx.x; int t = threadIdx.x;
  if (blk < 800){
    int b = blk / 100; int pixbase = (blk % 100) * 64;
    int lane = t & 63; int cg = t >> 6;
    for (int ci = 0; ci < 32; ++ci){
      int c = cg * 32 + ci;
      float v = x[(b * 128 + c) * NHW + pixbase + lane];
      unsigned short hi, lo; splitbf(v, hi, lo);
      tileH[lane * 132 + c] = hi;
      tileL[lane * 132 + c] = lo;
    }
    __syncthreads();
    for (int i = 0; i < 8; ++i){
      int slot = t + i * 256; int m = slot >> 5; int c = (slot & 31) * 4;
      uint2 vH = *reinterpret_cast<const uint2*>(&tileH[m * 132 + c]);
      uint2 vL = *reinterpret_cast<const uint2*>(&tileL[m * 132 + c]);
      *reinterpret_cast<uint2*>(xt  + (b * NHW + pixbase + m) * 128 + c) = vH;
      *reinterpret_cast<uint2*>(xtl + (b * NHW + pixbase + m) * 128 + c) = vL;
    }
    return;
  }
  int pblk = blk - 800;
  if (pblk < 144){
    int id = pblk * 256 + t;
    int lane = id & 63, ofrag = (id >> 6) & 15, kc = (id >> 10) & 3, n = id >> 12;
    int o = ofrag * 16 + (lane & 15), cb = kc * 32 + ((lane >> 4) & 3) * 8;
    float sc = gamma[o] * rsqrtf(var[o] + 1e-5f);       // BN scale folded in
    unsigned short h[8];
    for (int j = 0; j < 8; ++j) h[j] = f2bf(w_conv[(o * 128 + cb + j) * 9 + n] * sc);
    uint4 v;
    v.x = (unsigned)h[0] | ((unsigned)h[1] << 16);
    v.y = (unsigned)h[2] | ((unsigned)h[3] << 16);
    v.z = (unsigned)h[4] | ((unsigned)h[5] << 16);
    v.w = (unsigned)h[6] | ((unsigned)h[7] << 16);
    wf[id] = v;
  } else if (pblk < 180){
    int isLo = (pblk >= 162);
    int id = (pblk - (isLo ? 162 : 144)) * 256 + t;
    int lane = id & 63, ofrag = (id >> 6) & 1, kc = (id >> 7) & 3, tap = id >> 9;
    int o = ofrag * 16 + (lane & 15), cb = kc * 32 + ((lane >> 4) & 3) * 8;
    unsigned short h[8];
    for (int j = 0; j < 8; ++j){
      unsigned short hi = 0, lo = 0;
      if (o < 18) splitbf(w_pconv[(o * 128 + cb + j) * 9 + tap], hi, lo);
      h[j] = isLo ? lo : hi;
    }
    uint4 v;
    v.x = (unsigned)h[0] | ((unsigned)h[1] << 16);
    v.y = (unsigned)h[2] | ((unsigned)h[3] << 16);
    v.z = (unsigned)h[4] | ((unsigned)h[5] << 16);
    v.w = (unsigned)h[6] | ((unsigned)h[7] << 16);
    if (isLo) wpfL[id] = v; else wpfH[id] = v;
  } else {
    float sc = gamma[t] * rsqrtf(var[t] + 1e-5f);
    shift[t] = beta[t] - mean[t] * sc;
  }
}

// ---------------- offset conv + descriptor build (R13 standalone, proven) ----------------
__global__ __launch_bounds__(256, 6) void k_offconv(const unsigned short* __restrict__ xt,
                                                    const unsigned short* __restrict__ xtl,
                                                    const uint4* __restrict__ wpfH,
                                                    const uint4* __restrict__ wpfL,
                                                    const float* __restrict__ bpc,
                                                    const float* __restrict__ pn,
                                                    uint4* __restrict__ desc){
  int bid = blockIdx.x;
  int blk = (bid & 7) * 200 + (bid >> 3);          // XCD swizzle (1600 % 8 == 0)
  int b = blk / 200; int pixbase = (blk % 200) * 32;
  int t = threadIdx.x; int lane = t & 63; int wv = t >> 6;
  int og = wv & 1;
  int pf = wv >> 1;
  __shared__ short BtileH[32 * 136];
  __shared__ short BtileL[32 * 136];
  __shared__ float off_lds[32 * 20];

  f32x4 acc = (f32x4){0.f, 0.f, 0.f, 0.f};
  const unsigned short* xbH = xt  + (size_t)b * NHW * 128;
  const unsigned short* xbL = xtl + (size_t)b * NHW * 128;

  int m_i[4], c_i[4], h_i[4], w_i[4];
#pragma unroll
  for (int i = 0; i < 4; ++i){
    int slot = t + i * 256;
    m_i[i] = slot >> 5; c_i[i] = (slot & 31) * 4;
    int p = pixbase + m_i[i];
    h_i[i] = p / NPIX; w_i[i] = p % NPIX;
  }

  uint2 rH[4], rL[4];

#define LOADTAP(DH, DW)                                                        \
  _Pragma("unroll")                                                            \
  for (int i = 0; i < 4; ++i){                                                 \
    int h2 = h_i[i] + (DH), w2 = w_i[i] + (DW);                                \
    uint2 vH; vH.x = 0u; vH.y = 0u;                                            \
    uint2 vL; vL.x = 0u; vL.y = 0u;                                            \
    if ((unsigned)h2 < NPIX && (unsigned)w2 < NPIX){                           \
      int off = (h2 * NPIX + w2) * 128 + c_i[i];                               \
      vH = *reinterpret_cast<const uint2*>(xbH + off);                         \
      vL = *reinterpret_cast<const uint2*>(xbL + off);                         \
    }                                                                          \
    rH[i] = vH; rL[i] = vL;                                                    \
  }

#define WRITETILE()                                                            \
  _Pragma("unroll")                                                            \
  for (int i = 0; i < 4; ++i){                                                 \
    *reinterpret_cast<uint2*>(&BtileH[m_i[i] * 136 + c_i[i]]) = rH[i];         \
    *reinterpret_cast<uint2*>(&BtileL[m_i[i] * 136 + c_i[i]]) = rL[i];         \
  }

  LOADTAP(-1, -1)
  WRITETILE()
  __syncthreads();

#pragma unroll 1
  for (int tap = 0; tap < 9; ++tap){
    if (tap < 8){
      int dh2 = (tap + 1) / 3 - 1, dw2 = (tap + 1) % 3 - 1;
      LOADTAP(dh2, dw2)
    }
#pragma unroll
    for (int kc = 0; kc < 4; ++kc){
      int boff = (pf * 16 + (lane & 15)) * 136 + kc * 32 + ((lane >> 4) & 3) * 8;
      bf16x8 bH = *reinterpret_cast<const bf16x8*>(&BtileH[boff]);
      bf16x8 bL = *reinterpret_cast<const bf16x8*>(&BtileL[boff]);
      int widx = ((tap * 4 + kc) * 2 + og) * 64 + lane;
      bf16x8 aH = *reinterpret_cast<const bf16x8*>(&wpfH[widx]);
      bf16x8 aL = *reinterpret_cast<const bf16x8*>(&wpfL[widx]);
      acc = __builtin_amdgcn_mfma_f32_16x16x32_bf16(aH, bH, acc, 0, 0, 0);
      acc = __builtin_amdgcn_mfma_f32_16x16x32_bf16(aH, bL, acc, 0, 0, 0);
      acc = __builtin_amdgcn_mfma_f32_16x16x32_bf16(aL, bH, acc, 0, 0, 0);
      acc = __builtin_amdgcn_mfma_f32_16x16x32_bf16(aL, bL, acc, 0, 0, 0);
    }
    __syncthreads();
    if (tap < 8){
      WRITETILE()
      __syncthreads();
    }
  }

  int pl = pf * 16 + (lane & 15);
#pragma unroll
  for (int r = 0; r < 4; ++r){
    int o = og * 16 + ((lane >> 4) & 3) * 4 + r;
    if (o < 18) off_lds[pl * 20 + o] = acc[r] + bpc[o];
  }
  __syncthreads();

  for (int item = t; item < 288; item += 256){
    int m = item / 9, n = item % 9;
    int p = pixbase + m; int h = p / NPIX, w = p % NPIX;
    float px = (float)h + pn[n]     + off_lds[m * 20 + n];
    float py = (float)w + pn[9 + n] + off_lds[m * 20 + 9 + n];
    float flx = floorf(px), fly = floorf(py);
    float qltx = fminf(fmaxf(flx, 0.f), 79.f);
    float qrbx = fminf(fmaxf(flx + 1.f, 0.f), 79.f);
    float qlty = fminf(fmaxf(fly, 0.f), 79.f);
    float qrby = fminf(fmaxf(fly + 1.f, 0.f), 79.f);
    float pcx = fminf(fmaxf(px, 0.f), 79.f);
    float pcy = fminf(fmaxf(py, 0.f), 79.f);
    float dxl = 1.f + (qltx - pcx), dxr = 1.f - (qrbx - pcx);
    float dyl = 1.f + (qlty - pcy), dyr = 1.f - (qrby - pcy);
    unsigned ix_l = (unsigned)(int)qltx, ix_r = (unsigned)(int)qrbx;
    unsigned iy_l = (unsigned)(int)qlty, iy_r = (unsigned)(int)qrby;
    uint4 d;
    d.x = (ix_l * NPIX + iy_l) | ((ix_r * NPIX + iy_r) << 16);
    d.y = (ix_l * NPIX + iy_r) | ((ix_r * NPIX + iy_l) << 16);
    d.z = (unsigned)f2f16u(dxl * dyl) | ((unsigned)f2f16u(dxr * dyr) << 16);
    d.w = (unsigned)f2f16u(dxl * dyr) | ((unsigned)f2f16u(dxr * dyl) << 16);
    desc[(size_t)(b * 9 + n) * NHW + p] = d;
  }
#undef LOADTAP
#undef WRITETILE
}

// ---------------- k_gather: barrier-free bilinear combine -> frag-layout x_off ----------------
// Wave-unit u = (b, tap n, 16-px tile pxt). Gathers coalesced (4x256B segs),
// COMB bit-identical to R15, 16x16 transpose of 16B chunks via wave-private
// LDS (272B row stride, lgkmcnt-ordered, no barrier). Output per (unit,kc):
// contiguous 1KB holding the wave's B-fragment (lane l <- px l&15, q l>>4).
__global__ __launch_bounds__(256) void k_gather(const unsigned short* __restrict__ xt,
                                                const uint4* __restrict__ desc,
                                                char* __restrict__ x_off){
  int bid = blockIdx.x; int t = threadIdx.x; int lane = t & 63; int wv = t >> 6;
  __shared__ alignas(16) char tr[4][4352];     // 16 rows x 272B per wave
  int u = bid * 4 + wv;                        // 0..28799
  int b = u / 3600; int rem = u % 3600; int n = rem / 400; int pxt = rem % 400;
  const uint4* db = desc + (size_t)(b * 9 + n) * NHW + pxt * 16;
  const char* xb = (const char*)(xt + (size_t)b * NHW * 128);
  char* xo = x_off + ((size_t)((b * 9 + n) * 400 + pxt)) * 4096;
  int g = lane >> 4;
  unsigned cbv = (unsigned)((lane & 15) * 16);
  char* wb = &tr[wv][0];

#define GATH(G, D)                                                             \
  {                                                                            \
    G[0] = *reinterpret_cast<const u32x4*>(xb + (D.x & 0xffffu) * 256u + cbv); \
    G[1] = *reinterpret_cast<const u32x4*>(xb + (D.x >> 16)     * 256u + cbv); \
    G[2] = *reinterpret_cast<const u32x4*>(xb + (D.y & 0xffffu) * 256u + cbv); \
    G[3] = *reinterpret_cast<const u32x4*>(xb + (D.y >> 16)     * 256u + cbv); \
  }

#define COMBW(G, D, S)                                                         \
  {                                                                            \
    float w0 = f16u2f(D.z & 0xffffu), w1 = f16u2f(D.z >> 16);                  \
    float w2 = f16u2f(D.w & 0xffffu), w3 = f16u2f(D.w >> 16);                  \
    u32x4 pk;                                                                  \
    _Pragma("unroll")                                                          \
    for (int j = 0; j < 4; ++j){                                               \
      f32x2 a = w0 * bfp2f(G[0][j]) + w1 * bfp2f(G[1][j])                      \
              + w2 * bfp2f(G[2][j]) + w3 * bfp2f(G[3][j]);                     \
      pk[j] = pk_bf16(a.x, a.y);                                               \
    }                                                                          \
    *reinterpret_cast<u32x4*>(wb + ((S) * 4 + g) * 272 + cbv) = pk;            \
  }

  uint4 d0 = db[g], d1 = db[4 + g], d2 = db[8 + g], d3 = db[12 + g];
  u32x4 Ga[4], Gb[4];
  GATH(Ga, d0) GATH(Gb, d1)
  COMBW(Ga, d0, 0) GATH(Ga, d2)
  COMBW(Gb, d1, 1) GATH(Gb, d3)
  COMBW(Ga, d2, 2)
  COMBW(Gb, d3, 3)

  // transpose read + contiguous 1KB frag stores (same-wave LDS: lgkmcnt-ordered)
#pragma unroll
  for (int kc = 0; kc < 4; ++kc){
    u32x4 v = *reinterpret_cast<const u32x4*>(wb + (lane & 15) * 272 + kc * 64 + g * 16);
    *reinterpret_cast<u32x4*>(xo + kc * 1024 + lane * 16) = v;
  }
#undef GATH
#undef COMBW
}

// ---------------- k_gemm: LDS-free, barrier-free 256x51200x1152 GEMM ----------------
// Wave owns 16 px x 256 oc. Per K-chunk c=(n*4+kc): 1 coalesced 1KB B-frag
// load (depth-2 ping-pong) + 16 wf frags (of-groups of 4, fenced to cap
// liveness) + 16 MFMA into acc[16] (64 VGPR). 36 chunks. Epilogue BN+SiLU.
__global__ __launch_bounds__(256, 4) void k_gemm(const char* __restrict__ x_off,
                                                 const uint4* __restrict__ wf,
                                                 const float* __restrict__ shift,
                                                 float* __restrict__ out){
  int bid = blockIdx.x; int t = threadIdx.x; int lane = t & 63; int wv = t >> 6;
  int u = bid * 4 + wv;                        // 0..3199
  int b = u / 400; int pxt = u % 400;
  const char* xob = x_off + ((size_t)b * 9 * 400 + pxt) * 4096;

  f32x4 acc[16];
#pragma unroll
  for (int of = 0; of < 16; ++of) acc[of] = (f32x4){0.f, 0.f, 0.f, 0.f};

  bf16x8 Bc, Bn;
  Bc = *reinterpret_cast<const bf16x8*>(xob + lane * 16);   // chunk 0 (n=0,kc=0)

#pragma unroll 4
  for (int c = 0; c < 36; ++c){
    if (c < 35){
      int c1 = c + 1; int n1 = c1 >> 2, kc1 = c1 & 3;
      Bn = *reinterpret_cast<const bf16x8*>(xob + (size_t)n1 * 1638400 + kc1 * 1024 + lane * 16);
    }
    __builtin_amdgcn_s_setprio(1);
#pragma unroll
    for (int og = 0; og < 4; ++og){
      bf16x8 a0 = *reinterpret_cast<const bf16x8*>(&wf[(c * 16 + og * 4 + 0) * 64 + lane]);
      bf16x8 a1 = *reinterpret_cast<const bf16x8*>(&wf[(c * 16 + og * 4 + 1) * 64 + lane]);
      bf16x8 a2 = *reinterpret_cast<const bf16x8*>(&wf[(c * 16 + og * 4 + 2) * 64 + lane]);
      bf16x8 a3 = *reinterpret_cast<const bf16x8*>(&wf[(c * 16 + og * 4 + 3) * 64 + lane]);
      acc[og * 4 + 0] = __builtin_amdgcn_mfma_f32_16x16x32_bf16(a0, Bc, acc[og * 4 + 0], 0, 0, 0);
      acc[og * 4 + 1] = __builtin_amdgcn_mfma_f32_16x16x32_bf16(a1, Bc, acc[og * 4 + 1], 0, 0, 0);
      acc[og * 4 + 2] = __builtin_amdgcn_mfma_f32_16x16x32_bf16(a2, Bc, acc[og * 4 + 2], 0, 0, 0);
      acc[og * 4 + 3] = __builtin_amdgcn_mfma_f32_16x16x32_bf16(a3, Bc, acc[og * 4 + 3], 0, 0, 0);
      __builtin_amdgcn_sched_barrier(0);
    }
    __builtin_amdgcn_s_setprio(0);
    Bc = Bn;
  }

  int px = pxt * 16 + (lane & 15);
#pragma unroll
  for (int of = 0; of < 16; ++of){
    int oc0 = of * 16 + (lane >> 4) * 4;
#pragma unroll
    for (int r = 0; r < 4; ++r){
      int oc = oc0 + r;
      float v = acc[of][r] + shift[oc];
      out[((size_t)b * 256 + oc) * NHW + px] = fast_silu(v);
    }
  }
}

// ---------------- fallback: R15 fused kernel (proven 114.6us path) ----------------
__global__ __launch_bounds__(256, 4) void k_fused(const unsigned short* __restrict__ xt,
                                                  const unsigned short* __restrict__ xtl,
                                                  const uint4* __restrict__ wpfH,
                                                  const uint4* __restrict__ wpfL,
                                                  const float* __restrict__ bpc,
                                                  const float* __restrict__ pn,
                                                  const uint4* __restrict__ wf,
                                                  const float* __restrict__ shift,
                                                  float* __restrict__ out){
  int bid = blockIdx.x;
  int blk = (bid & 7) * 200 + (bid >> 3);
  int b = blk / 200; int pixbase = (blk % 200) * 32;
  int t = threadIdx.x; int lane = t & 63;

  __shared__ alignas(16) char smem[24576];
  short* BtileH  = (short*)(smem);
  short* BtileL  = (short*)(smem + 8704);
  float* off_lds = (float*)(smem + 17408);
  uint4* descL   = (uint4*)(smem + 19968);

  {
    int wv = t >> 6; int og = wv & 1; int pf = wv >> 1;
    f32x4 acc = (f32x4){0.f, 0.f, 0.f, 0.f};
    const unsigned short* xbH = xt  + (size_t)b * NHW * 128;
    const unsigned short* xbL = xtl + (size_t)b * NHW * 128;

    int m_i[4], c_i[4], h_i[4], w_i[4];
#pragma unroll
    for (int i = 0; i < 4; ++i){
      int slot = t + i * 256;
      m_i[i] = slot >> 5; c_i[i] = (slot & 31) * 4;
      int p = pixbase + m_i[i];
      h_i[i] = p / NPIX; w_i[i] = p % NPIX;
    }

    uint2 rH[4], rL[4];

#define LOADTAP(DH, DW)                                                        \
  _Pragma("unroll")                                                            \
  for (int i = 0; i < 4; ++i){                                                 \
    int h2 = h_i[i] + (DH), w2 = w_i[i] + (DW);                                \
    uint2 vH; vH.x = 0u; vH.y = 0u;                                            \
    uint2 vL; vL.x = 0u; vL.y = 0u;                                            \
    if ((unsigned)h2 < NPIX && (unsigned)w2 < NPIX){                           \
      int off = (h2 * NPIX + w2) * 128 + c_i[i];                               \
      vH = *reinterpret_cast<const uint2*>(xbH + off);                         \
      vL = *reinterpret_cast<const uint2*>(xbL + off);                         \
    }                                                                          \
    rH[i] = vH; rL[i] = vL;                                                    \
  }

#define WRITETILE()                                                            \
  _Pragma("unroll")                                                            \
  for (int i = 0; i < 4; ++i){                                                 \
    *reinterpret_cast<uint2*>(&BtileH[m_i[i] * 136 + c_i[i]]) = rH[i];         \
    *reinterpret_cast<uint2*>(&BtileL[m_i[i] * 136 + c_i[i]]) = rL[i];         \
  }

    LOADTAP(-1, -1)
    WRITETILE()
    __syncthreads();

#pragma unroll 1
    for (int tap = 0; tap < 9; ++tap){
      if (tap < 8){
        int dh2 = (tap + 1) / 3 - 1, dw2 = (tap + 1) % 3 - 1;
        LOADTAP(dh2, dw2)
      }
#pragma unroll
      for (int kc = 0; kc < 4; ++kc){
        int boff = (pf * 16 + (lane & 15)) * 136 + kc * 32 + ((lane >> 4) & 3) * 8;
        bf16x8 bH = *reinterpret_cast<const bf16x8*>(&BtileH[boff]);
        bf16x8 bL = *reinterpret_cast<const bf16x8*>(&BtileL[boff]);
        int widx = ((tap * 4 + kc) * 2 + og) * 64 + lane;
        bf16x8 aH = *reinterpret_cast<const bf16x8*>(&wpfH[widx]);
        bf16x8 aL = *reinterpret_cast<const bf16x8*>(&wpfL[widx]);
        acc = __builtin_amdgcn_mfma_f32_16x16x32_bf16(aH, bH, acc, 0, 0, 0);
        acc = __builtin_amdgcn_mfma_f32_16x16x32_bf16(aH, bL, acc, 0, 0, 0);
        acc = __builtin_amdgcn_mfma_f32_16x16x32_bf16(aL, bH, acc, 0, 0, 0);
        acc = __builtin_amdgcn_mfma_f32_16x16x32_bf16(aL, bL, acc, 0, 0, 0);
      }
      __syncthreads();
      if (tap < 8){
        WRITETILE()
        __syncthreads();
      }
    }

    int pl = pf * 16 + (lane & 15);
#pragma unroll
    for (int r = 0; r < 4; ++r){
      int o = og * 16 + ((lane >> 4) & 3) * 4 + r;
      if (o < 18) off_lds[pl * 20 + o] = acc[r] + bpc[o];
    }
    __syncthreads();

    for (int item = t; item < 288; item += 256){
      int m = item / 9, n = item % 9;
      int p = pixbase + m; int h = p / NPIX, w = p % NPIX;
      float px = (float)h + pn[n]     + off_lds[m * 20 + n];
      float py = (float)w + pn[9 + n] + off_lds[m * 20 + 9 + n];
      float flx = floorf(px), fly = floorf(py);
      float qltx = fminf(fmaxf(flx, 0.f), 79.f);
      float qrbx = fminf(fmaxf(flx + 1.f, 0.f), 79.f);
      float qlty = fminf(fmaxf(fly, 0.f), 79.f);
      float qrby = fminf(fmaxf(fly + 1.f, 0.f), 79.f);
      float pcx = fminf(fmaxf(px, 0.f), 79.f);
      float pcy = fminf(fmaxf(py, 0.f), 79.f);
      float dxl = 1.f + (qltx - pcx), dxr = 1.f - (qrbx - pcx);
      float dyl = 1.f + (qlty - pcy), dyr = 1.f - (qrby - pcy);
      unsigned ix_l = (unsigned)(int)qltx, ix_r = (unsigned)(int)qrbx;
      unsigned iy_l = (unsigned)(int)qlty, iy_r = (unsigned)(int)qrby;
      uint4 d;
      d.x = (ix_l * NPIX + iy_l) | ((ix_r * NPIX + iy_r) << 16);
      d.y = (ix_l * NPIX + iy_r) | ((ix_r * NPIX + iy_l) << 16);
      d.z = (unsigned)f2f16u(dxl * dyl) | ((unsigned)f2f16u(dxr * dyr) << 16);
      d.w = (unsigned)f2f16u(dxl * dyr) | ((unsigned)f2f16u(dxr * dyl) << 16);
      descL[n * 32 + m] = d;
    }
#undef LOADTAP
#undef WRITETILE
  }
  __syncthreads();
  __builtin_amdgcn_sched_barrier(0);

  {
    int ow = t >> 6;
    char* A_lds0 = smem;
    const char* xb = (const char*)(xt + (size_t)b * NHW * 128);

    int m0 = t >> 4;
    int m1 = m0 + 16;
    int cb = (t & 15) * 16;
    int ls0 = m0 * 256 + (cb ^ ((m0 & 7) << 4));
    int ls1 = m1 * 256 + (cb ^ ((m1 & 7) << 4));

    f32x4 acc[4][2];
#pragma unroll
    for (int of = 0; of < 4; ++of)
#pragma unroll
      for (int pf = 0; pf < 2; ++pf)
        acc[of][pf] = (f32x4){0.f, 0.f, 0.f, 0.f};

    u32x4 GX[4], GY[4];
    uint2 zwX, zwY;
    uint4 dB0, dB1;

#define DLD(N, M) descL[(N) * 32 + (M)]

#define ISSUE_X()                                                              \
  {                                                                            \
    zwX.x = dB0.z; zwX.y = dB0.w;                                              \
    GX[0] = *reinterpret_cast<const u32x4*>(xb + (dB0.x & 0xffffu) * 256u + (unsigned)cb); \
    GX[1] = *reinterpret_cast<const u32x4*>(xb + (dB0.x >> 16)     * 256u + (unsigned)cb); \
    GX[2] = *reinterpret_cast<const u32x4*>(xb + (dB0.y & 0xffffu) * 256u + (unsigned)cb); \
    GX[3] = *reinterpret_cast<const u32x4*>(xb + (dB0.y >> 16)     * 256u + (unsigned)cb); \
  }

#define ISSUE_Y()                                                              \
  {                                                                            \
    zwY.x = dB1.z; zwY.y = dB1.w;                                              \
    GY[0] = *reinterpret_cast<const u32x4*>(xb + (dB1.x & 0xffffu) * 256u + (unsigned)cb); \
    GY[1] = *reinterpret_cast<const u32x4*>(xb + (dB1.x >> 16)     * 256u + (unsigned)cb); \
    GY[2] = *reinterpret_cast<const u32x4*>(xb + (dB1.y & 0xffffu) * 256u + (unsigned)cb); \
    GY[3] = *reinterpret_cast<const u32x4*>(xb + (dB1.y >> 16)     * 256u + (unsigned)cb); \
  }

#define COMB(G, ZW, LSO, WB)                                                   \
  {                                                                            \
    float w0 = f16u2f(ZW.x & 0xffffu), w1 = f16u2f(ZW.x >> 16);                \
    float w2 = f16u2f(ZW.y & 0xffffu), w3 = f16u2f(ZW.y >> 16);                \
    u32x4 pk;                                                                  \
    _Pragma("unroll")                                                          \
    for (int j = 0; j < 4; ++j){                                               \
      f32x2 a = w0 * bfp2f(G[0][j]) + w1 * bfp2f(G[1][j])                      \
              + w2 * bfp2f(G[2][j]) + w3 * bfp2f(G[3][j]);                     \
      pk[j] = pk_bf16(a.x, a.y);                                               \
    }                                                                          \
    *reinterpret_cast<u32x4*>((WB) + (LSO)) = pk;                              \
  }

#define MFMA_HALF(NN, KCA, KCB)                                                \
  {                                                                            \
    const char* ab = A_lds0 + ((NN) & 1) * 8192;                               \
    __builtin_amdgcn_s_setprio(1);                                             \
    _Pragma("unroll")                                                          \
    for (int kc = (KCA); kc <= (KCB); ++kc){                                   \
      bf16x8 bfrk[2];                                                          \
      _Pragma("unroll")                                                        \
      for (int pf = 0; pf < 2; ++pf){                                          \
        int row = pf * 16 + (lane & 15);                                       \
        bfrk[pf] = *reinterpret_cast<const bf16x8*>(                           \
            ab + row * 256 + ((kc * 64 + ((lane >> 4) & 3) * 16) ^ ((row & 7) << 4))); \
      }                                                                        \
      _Pragma("unroll")                                                        \
      for (int of = 0; of < 4; ++of){                                          \
        bf16x8 afr = *reinterpret_cast<const bf16x8*>(                         \
            &wf[((((NN) * 4 + kc) * 16) + ow * 4 + of) * 64 + lane]);          \
        _Pragma("unroll")                                                      \
        for (int pf = 0; pf < 2; ++pf)                                         \
          acc[of][pf] = __builtin_amdgcn_mfma_f32_16x16x32_bf16(afr, bfrk[pf], acc[of][pf], 0, 0, 0); \
      }                                                                        \
    }                                                                          \
    __builtin_amdgcn_s_setprio(0);                                             \
  }

#define STEP(NN)                                                               \
  {                                                                            \
    if ((NN) < 8){ ISSUE_X() }                                                 \
    if ((NN) < 7){ dB0 = DLD((NN) + 2, m0); }                                  \
    MFMA_HALF(NN, 0, 1)                                                        \
    if ((NN) < 8){                                                             \
      COMB(GX, zwX, ls0, A_lds0 + (((NN) + 1) & 1) * 8192)                     \
      __builtin_amdgcn_sched_barrier(0);                                       \
      ISSUE_Y()                                                                \
    }                                                                          \
    if ((NN) < 7){ dB1 = DLD((NN) + 2, m1); }                                  \
    MFMA_HALF(NN, 2, 3)                                                        \
    if ((NN) < 8){                                                             \
      COMB(GY, zwY, ls1, A_lds0 + (((NN) + 1) & 1) * 8192)                     \
    }                                                                          \
    __syncthreads();                                                           \
  }

    dB0 = DLD(0, m0); dB1 = DLD(0, m1);
    ISSUE_X()
    COMB(GX, zwX, ls0, A_lds0)
    __builtin_amdgcn_sched_barrier(0);
    ISSUE_Y()
    COMB(GY, zwY, ls1, A_lds0)
    dB0 = DLD(1, m0); dB1 = DLD(1, m1);
    __syncthreads();

    STEP(0) STEP(1) STEP(2) STEP(3) STEP(4) STEP(5) STEP(6) STEP(7) STEP(8)

#pragma unroll
    for (int of = 0; of < 4; ++of)
#pragma unroll
      for (int pf = 0; pf < 2; ++pf){
        int pix = pixbase + pf * 16 + (lane & 15);
#pragma unroll
        for (int r = 0; r < 4; ++r){
          int o = ow * 64 + of * 16 + ((lane >> 4) & 3) * 4 + r;
          float v = acc[of][pf][r] + shift[o];
          out[(size_t)(b * 256 + o) * NHW + pix] = fast_silu(v);
        }
      }
#undef DLD
#undef ISSUE_X
#undef ISSUE_Y
#undef COMB
#undef MFMA_HALF
#undef STEP
  }
}

extern "C" void kernel_launch(void* const* d_in, const int* in_sizes, int n_in,
                              void* d_out, int out_size, void* d_ws, size_t ws_size,
                              hipStream_t stream){
  const float* x       = (const float*)d_in[0];
  const float* w_pconv = (const float*)d_in[1];
  const float* b_pconv = (const float*)d_in[2];
  const float* w_conv  = (const float*)d_in[3];
  const float* gamma   = (const float*)d_in[4];
  const float* beta    = (const float*)d_in[5];
  const float* mean    = (const float*)d_in[6];
  const float* var     = (const float*)d_in[7];
  const float* pn      = (const float*)d_in[8];

  char* ws = (char*)d_ws;
  unsigned short* xt  = (unsigned short*)(ws + 0);           // 13,107,200 B
  unsigned short* xtl = (unsigned short*)(ws + 13107200);    // 13,107,200 B
  uint4* desc         = (uint4*)(ws + 26214400);             //  7,372,800 B
  uint4* wf           = (uint4*)(ws + 33587200);             //    589,824 B
  uint4* wpfH         = (uint4*)(ws + 34177024);             //     73,728 B
  uint4* wpfL         = (uint4*)(ws + 34250752);             //     73,728 B
  float* shift        = (float*)(ws + 34324480);             //      1,024 B
  char*  x_off        = (char*)(ws + 34325504);              // 117,964,800 B
  float* out          = (float*)d_out;

  const size_t NEED = 34325504ull + 117964800ull;            // ~152.3 MB

  k_pre<<<981, 256, 0, stream>>>(x, w_conv, w_pconv, gamma, beta, mean, var,
                                 xt, xtl, wf, wpfH, wpfL, shift);
  if (ws_size >= NEED){
    k_offconv<<<1600, 256, 0, stream>>>(xt, xtl, wpfH, wpfL, b_pconv, pn, desc);
    k_gather<<<7200, 256, 0, stream>>>(xt, desc, x_off);
    k_gemm<<<800, 256, 0, stream>>>(x_off, wf, shift, out);
  } else {
    k_fused<<<1600, 256, 0, stream>>>(xt, xtl, wpfH, wpfL, b_pconv, pn, wf, shift, out);
  }
}

// Round 8
// 128.916 us; speedup vs baseline: 1.4465x; 1.4465x over previous
//
#include <hip/hip_runtime.h>
#include <hip/hip_bf16.h>

// LDConv (deformable sampling + (N,1) conv + BN + SiLU) for MI355X.
//
// Round-21. R20's decomposition ablation finally attributed the cost:
// pure GEMM (k_gemm: no LDS/barriers/gathers, coalesced 1KB loads) took
// 106us streaming 1.84 GB of wf from L2 = 17.4 TB/s. Fused phase-2 moves
// 1.4 GB in 73us = 19 TB/s. Same rate -> the kernel family is pinned at
// the TRUE pure-streaming L2 delivery ceiling (~18-19 TB/s; the 34.5
// µbench figure includes L1 reuse). Six neutral schedule experiments
// (R14-R19) are explained: same bytes => same time.
// R18 was a FALSE test of the BW theory: its pw-split waves duplicated
// wf reads (8 waves x 144 KB/block) so chip wf traffic never dropped.
//
// This round truly halves wf bytes: k_main64 = 64px x 256oc blocks where
// EACH wave covers all 64 px for its 64-oc slice (acc 4x4xf32x4 = 64 VGPR,
// proven in R20's k_gemm). Per block wf = 576 KB covers 64 px -> chip wf
// 921 -> 460 MB; phase-2 L2 bytes 1.4 -> 0.93 GB (-33%).
//  - grid 800 (XCD swizzle, 800%8==0), 4 waves, launch_bounds(256,3)
//    (~134 peak regs < 170 cap; 3 blk/CU; A_lds 32KB dbuf XOR-swizzled).
//  - R15 STEP schedule extended: 4 gather sets serialized (16-reg G
//    liveness), 4 kc quarters, desc (global, from proven k_offconv)
//    loaded one step ahead, COMB reads dB.z/.w directly.
//  - k_pre, k_offconv byte-identical proven versions.
// Spill tripwire: WRITE_SIZE must stay ~51 MB.

typedef __attribute__((ext_vector_type(8))) short bf16x8;
typedef __attribute__((ext_vector_type(4))) float f32x4;
typedef __attribute__((ext_vector_type(2))) float f32x2;
typedef __attribute__((ext_vector_type(4))) unsigned int u32x4;

#define NHW 6400
#define NPIX 80

__device__ __forceinline__ unsigned short f2bf(float f){
  __hip_bfloat16 h = __float2bfloat16(f);
  unsigned short u; __builtin_memcpy(&u, &h, 2); return u;
}
__device__ __forceinline__ f32x2 bfp2f(unsigned int u){
  union { unsigned int i; float f; } a, b;
  a.i = u << 16; b.i = u & 0xffff0000u;
  f32x2 r; r.x = a.f; r.y = b.f; return r;
}
__device__ __forceinline__ unsigned pk_bf16(float a, float b){
  unsigned r;
  asm("v_cvt_pk_bf16_f32 %0, %1, %2" : "=v"(r) : "v"(a), "v"(b));
  return r;
}
__device__ __forceinline__ void splitbf(float v, unsigned short& hi, unsigned short& lo){
  hi = f2bf(v);
  union { unsigned int i; float f; } h; h.i = (unsigned)hi << 16;
  lo = f2bf(v - h.f);
}
__device__ __forceinline__ float f16u2f(unsigned int u){
  unsigned short s = (unsigned short)u; _Float16 h;
  __builtin_memcpy(&h, &s, 2); return (float)h;
}
__device__ __forceinline__ unsigned short f2f16u(float f){
  _Float16 h = (_Float16)f; unsigned short s;
  __builtin_memcpy(&s, &h, 2); return s;
}
__device__ __forceinline__ float fast_silu(float v){
  float e, r;
  asm("v_exp_f32 %0, %1" : "=v"(e) : "v"(v * -1.44269504088896f)); // exp(-v)
  asm("v_rcp_f32 %0, %1" : "=v"(r) : "v"(1.0f + e));
  return v * r;
}

// ---------------- merged: transpose (blk<800) + weight prep ----------------
__global__ __launch_bounds__(256) void k_pre(const float* __restrict__ x,
                                             const float* __restrict__ w_conv,
                                             const float* __restrict__ w_pconv,
                                             const float* __restrict__ gamma,
                                             const float* __restrict__ beta,
                                             const float* __restrict__ mean,
                                             const float* __restrict__ var,
                                             unsigned short* __restrict__ xt,
                                             unsigned short* __restrict__ xtl,
                                             uint4* __restrict__ wf,
                                             uint4* __restrict__ wpfH,
                                             uint4* __restrict__ wpfL,
                                             float* __restrict__ shift){
  __shared__ unsigned short tileH[64 * 132];
  __shared__ unsigned short tileL[64 * 132];
  int blk = blockIdx.x; int t = threadIdx.x;
  if (blk < 800){
    int b = blk / 100; int pixbase = (blk % 100) * 64;
    int lane = t & 63; int cg = t >> 6;
    for (int ci = 0; ci < 32; ++ci){
      int c = cg * 32 + ci;
      float v = x[(b * 128 + c) * NHW + pixbase + lane];
      unsigned short hi, lo; splitbf(v, hi, lo);
      tileH[lane * 132 + c] = hi;
      tileL[lane * 132 + c] = lo;
    }
    __syncthreads();
    for (int i = 0; i < 8; ++i){
      int slot = t + i * 256; int m = slot >> 5; int c = (slot & 31) * 4;
      uint2 vH = *reinterpret_cast<const uint2*>(&tileH[m * 132 + c]);
      uint2 vL = *reinterpret_cast<const uint2*>(&tileL[m * 132 + c]);
      *reinterpret_cast<uint2*>(xt  + (b * NHW + pixbase + m) * 128 + c) = vH;
      *reinterpret_cast<uint2*>(xtl + (b * NHW + pixbase + m) * 128 + c) = vL;
    }
    return;
  }
  int pblk = blk - 800;
  if (pblk < 144){
    int id = pblk * 256 + t;
    int lane = id & 63, ofrag = (id >> 6) & 15, kc = (id >> 10) & 3, n = id >> 12;
    int o = ofrag * 16 + (lane & 15), cb = kc * 32 + ((lane >> 4) & 3) * 8;
    float sc = gamma[o] * rsqrtf(var[o] + 1e-5f);       // BN scale folded in
    unsigned short h[8];
    for (int j = 0; j < 8; ++j) h[j] = f2bf(w_conv[(o * 128 + cb + j) * 9 + n] * sc);
    uint4 v;
    v.x = (unsigned)h[0] | ((unsigned)h[1] << 16);
    v.y = (unsigned)h[2] | ((unsigned)h[3] << 16);
    v.z = (unsigned)h[4] | ((unsigned)h[5] << 16);
    v.w = (unsigned)h[6] | ((unsigned)h[7] << 16);
    wf[id] = v;
  } else if (pblk < 180){
    int isLo = (pblk >= 162);
    int id = (pblk - (isLo ? 162 : 144)) * 256 + t;
    int lane = id & 63, ofrag = (id >> 6) & 1, kc = (id >> 7) & 3, tap = id >> 9;
    int o = ofrag * 16 + (lane & 15), cb = kc * 32 + ((lane >> 4) & 3) * 8;
    unsigned short h[8];
    for (int j = 0; j < 8; ++j){
      unsigned short hi = 0, lo = 0;
      if (o < 18) splitbf(w_pconv[(o * 128 + cb + j) * 9 + tap], hi, lo);
      h[j] = isLo ? lo : hi;
    }
    uint4 v;
    v.x = (unsigned)h[0] | ((unsigned)h[1] << 16);
    v.y = (unsigned)h[2] | ((unsigned)h[3] << 16);
    v.z = (unsigned)h[4] | ((unsigned)h[5] << 16);
    v.w = (unsigned)h[6] | ((unsigned)h[7] << 16);
    if (isLo) wpfL[id] = v; else wpfH[id] = v;
  } else {
    float sc = gamma[t] * rsqrtf(var[t] + 1e-5f);
    shift[t] = beta[t] - mean[t] * sc;
  }
}

// ---------------- offset conv + descriptor build (proven standalone) ----------------
__global__ __launch_bounds__(256, 6) void k_offconv(const unsigned short* __restrict__ xt,
                                                    const unsigned short* __restrict__ xtl,
                                                    const uint4* __restrict__ wpfH,
                                                    const uint4* __restrict__ wpfL,
                                                    const float* __restrict__ bpc,
                                                    const float* __restrict__ pn,
                                                    uint4* __restrict__ desc){
  int bid = blockIdx.x;
  int blk = (bid & 7) * 200 + (bid >> 3);          // XCD swizzle (1600 % 8 == 0)
  int b = blk / 200; int pixbase = (blk % 200) * 32;
  int t = threadIdx.x; int lane = t & 63; int wv = t >> 6;
  int og = wv & 1;
  int pf = wv >> 1;
  __shared__ short BtileH[32 * 136];
  __shared__ short BtileL[32 * 136];
  __shared__ float off_lds[32 * 20];

  f32x4 acc = (f32x4){0.f, 0.f, 0.f, 0.f};
  const unsigned short* xbH = xt  + (size_t)b * NHW * 128;
  const unsigned short* xbL = xtl + (size_t)b * NHW * 128;

  int m_i[4], c_i[4], h_i[4], w_i[4];
#pragma unroll
  for (int i = 0; i < 4; ++i){
    int slot = t + i * 256;
    m_i[i] = slot >> 5; c_i[i] = (slot & 31) * 4;
    int p = pixbase + m_i[i];
    h_i[i] = p / NPIX; w_i[i] = p % NPIX;
  }

  uint2 rH[4], rL[4];

#define LOADTAP(DH, DW)                                                        \
  _Pragma("unroll")                                                            \
  for (int i = 0; i < 4; ++i){                                                 \
    int h2 = h_i[i] + (DH), w2 = w_i[i] + (DW);                                \
    uint2 vH; vH.x = 0u; vH.y = 0u;                                            \
    uint2 vL; vL.x = 0u; vL.y = 0u;                                            \
    if ((unsigned)h2 < NPIX && (unsigned)w2 < NPIX){                           \
      int off = (h2 * NPIX + w2) * 128 + c_i[i];                               \
      vH = *reinterpret_cast<const uint2*>(xbH + off);                         \
      vL = *reinterpret_cast<const uint2*>(xbL + off);                         \
    }                                                                          \
    rH[i] = vH; rL[i] = vL;                                                    \
  }

#define WRITETILE()                                                            \
  _Pragma("unroll")                                                            \
  for (int i = 0; i < 4; ++i){                                                 \
    *reinterpret_cast<uint2*>(&BtileH[m_i[i] * 136 + c_i[i]]) = rH[i];         \
    *reinterpret_cast<uint2*>(&BtileL[m_i[i] * 136 + c_i[i]]) = rL[i];         \
  }

  LOADTAP(-1, -1)
  WRITETILE()
  __syncthreads();

#pragma unroll 1
  for (int tap = 0; tap < 9; ++tap){
    if (tap < 8){
      int dh2 = (tap + 1) / 3 - 1, dw2 = (tap + 1) % 3 - 1;
      LOADTAP(dh2, dw2)
    }
#pragma unroll
    for (int kc = 0; kc < 4; ++kc){
      int boff = (pf * 16 + (lane & 15)) * 136 + kc * 32 + ((lane >> 4) & 3) * 8;
      bf16x8 bH = *reinterpret_cast<const bf16x8*>(&BtileH[boff]);
      bf16x8 bL = *reinterpret_cast<const bf16x8*>(&BtileL[boff]);
      int widx = ((tap * 4 + kc) * 2 + og) * 64 + lane;
      bf16x8 aH = *reinterpret_cast<const bf16x8*>(&wpfH[widx]);
      bf16x8 aL = *reinterpret_cast<const bf16x8*>(&wpfL[widx]);
      acc = __builtin_amdgcn_mfma_f32_16x16x32_bf16(aH, bH, acc, 0, 0, 0);
      acc = __builtin_amdgcn_mfma_f32_16x16x32_bf16(aH, bL, acc, 0, 0, 0);
      acc = __builtin_amdgcn_mfma_f32_16x16x32_bf16(aL, bH, acc, 0, 0, 0);
      acc = __builtin_amdgcn_mfma_f32_16x16x32_bf16(aL, bL, acc, 0, 0, 0);
    }
    __syncthreads();
    if (tap < 8){
      WRITETILE()
      __syncthreads();
    }
  }

  int pl = pf * 16 + (lane & 15);
#pragma unroll
  for (int r = 0; r < 4; ++r){
    int o = og * 16 + ((lane >> 4) & 3) * 4 + r;
    if (o < 18) off_lds[pl * 20 + o] = acc[r] + bpc[o];
  }
  __syncthreads();

  for (int item = t; item < 288; item += 256){
    int m = item / 9, n = item % 9;
    int p = pixbase + m; int h = p / NPIX, w = p % NPIX;
    float px = (float)h + pn[n]     + off_lds[m * 20 + n];
    float py = (float)w + pn[9 + n] + off_lds[m * 20 + 9 + n];
    float flx = floorf(px), fly = floorf(py);
    float qltx = fminf(fmaxf(flx, 0.f), 79.f);
    float qrbx = fminf(fmaxf(flx + 1.f, 0.f), 79.f);
    float qlty = fminf(fmaxf(fly, 0.f), 79.f);
    float qrby = fminf(fmaxf(fly + 1.f, 0.f), 79.f);
    float pcx = fminf(fmaxf(px, 0.f), 79.f);
    float pcy = fminf(fmaxf(py, 0.f), 79.f);
    float dxl = 1.f + (qltx - pcx), dxr = 1.f - (qrbx - pcx);
    float dyl = 1.f + (qlty - pcy), dyr = 1.f - (qrby - pcy);
    unsigned ix_l = (unsigned)(int)qltx, ix_r = (unsigned)(int)qrbx;
    unsigned iy_l = (unsigned)(int)qlty, iy_r = (unsigned)(int)qrby;
    uint4 d;
    d.x = (ix_l * NPIX + iy_l) | ((ix_r * NPIX + iy_r) << 16);
    d.y = (ix_l * NPIX + iy_r) | ((ix_r * NPIX + iy_l) << 16);
    d.z = (unsigned)f2f16u(dxl * dyl) | ((unsigned)f2f16u(dxr * dyr) << 16);
    d.w = (unsigned)f2f16u(dxl * dyr) | ((unsigned)f2f16u(dxr * dyl) << 16);
    desc[(size_t)(b * 9 + n) * NHW + p] = d;
  }
#undef LOADTAP
#undef WRITETILE
}

// ---------------- k_main64: 64px x 256oc gather GEMM, per-wave full-px coverage ----------------
// Wave = 64 px x 64 oc: per kc reads 4 B-frags (all 64 px from A_lds) x 4
// wf frags -> 16 MFMA; acc[4][4] = 64 VGPR. Block wf = 576 KB covers 64 px
// -> chip wf 460 MB (was 921). A_lds: [2 buf][64 rows][256 B], XOR swizzle
// byte^=(row&7)<<4 (row&7 invariant across the 4 16-row sets).
// STEP: 4 serialized gather sets (16-reg G liveness), desc one step ahead.
__global__ __launch_bounds__(256, 3) void k_main64(const unsigned short* __restrict__ xt,
                                                   const uint4* __restrict__ desc,
                                                   const uint4* __restrict__ wf,
                                                   const float* __restrict__ shift,
                                                   float* __restrict__ out){
  int bid = blockIdx.x;
  int blk = (bid & 7) * 100 + (bid >> 3);          // XCD swizzle (800 % 8 == 0)
  int b = blk / 100; int pixbase = (blk % 100) * 64;
  int t = threadIdx.x; int lane = t & 63; int ow = t >> 6;
  __shared__ alignas(16) char A_lds[2][64 * 256];  // 32 KB

  const char* xb = (const char*)(xt + (size_t)b * NHW * 128);
  const uint4* descb = desc + (size_t)b * 9 * NHW + pixbase;

  int mrow = t >> 4;          // 0..15 (set s covers rows s*16+mrow)
  int cb = (t & 15) * 16;     // byte col 0..240
  int lsw = cb ^ ((mrow & 7) << 4);   // (m&7)==(mrow&7) since 16|s*16

#define M(S)  (mrow + (S) * 16)
#define LS(S) ((mrow + (S) * 16) * 256 + lsw)

  f32x4 acc[4][4];
#pragma unroll
  for (int of = 0; of < 4; ++of)
#pragma unroll
    for (int pf = 0; pf < 4; ++pf)
      acc[of][pf] = (f32x4){0.f, 0.f, 0.f, 0.f};

  u32x4 G[4];                  // single gather set live at a time (16 regs)
  uint4 dB0, dB1, dB2, dB3;    // per-set descriptors (named: no dyn indexing)

#define ISSUE(D)                                                               \
  {                                                                            \
    G[0] = *reinterpret_cast<const u32x4*>(xb + (D.x & 0xffffu) * 256u + (unsigned)cb); \
    G[1] = *reinterpret_cast<const u32x4*>(xb + (D.x >> 16)     * 256u + (unsigned)cb); \
    G[2] = *reinterpret_cast<const u32x4*>(xb + (D.y & 0xffffu) * 256u + (unsigned)cb); \
    G[3] = *reinterpret_cast<const u32x4*>(xb + (D.y >> 16)     * 256u + (unsigned)cb); \
  }

#define COMB(D, LSO, WB)                                                       \
  {                                                                            \
    float w0 = f16u2f(D.z & 0xffffu), w1 = f16u2f(D.z >> 16);                  \
    float w2 = f16u2f(D.w & 0xffffu), w3 = f16u2f(D.w >> 16);                  \
    u32x4 pk;                                                                  \
    _Pragma("unroll")                                                          \
    for (int j = 0; j < 4; ++j){                                               \
      f32x2 a = w0 * bfp2f(G[0][j]) + w1 * bfp2f(G[1][j])                      \
              + w2 * bfp2f(G[2][j]) + w3 * bfp2f(G[3][j]);                     \
      pk[j] = pk_bf16(a.x, a.y);                                               \
    }                                                                          \
    *reinterpret_cast<u32x4*>((WB) + (LSO)) = pk;                              \
  }

// one kc quarter: 4 B-frags (64 px) x 4 wf frags (64 oc) = 16 MFMA
#define MFMA_Q(NN, KC)                                                         \
  {                                                                            \
    const char* ab = &A_lds[(NN) & 1][0];                                      \
    __builtin_amdgcn_s_setprio(1);                                             \
    bf16x8 bfrk[4];                                                            \
    _Pragma("unroll")                                                          \
    for (int pf = 0; pf < 4; ++pf){                                            \
      int row = pf * 16 + (lane & 15);                                         \
      bfrk[pf] = *reinterpret_cast<const bf16x8*>(                             \
          ab + row * 256 + (((KC) * 64 + ((lane >> 4) & 3) * 16) ^ ((row & 7) << 4))); \
    }                                                                          \
    _Pragma("unroll")                                                          \
    for (int of = 0; of < 4; ++of){                                            \
      bf16x8 afr = *reinterpret_cast<const bf16x8*>(                           \
          &wf[((((NN) * 4 + (KC)) * 16) + ow * 4 + of) * 64 + lane]);          \
      _Pragma("unroll")                                                        \
      for (int pf = 0; pf < 4; ++pf)                                           \
        acc[of][pf] = __builtin_amdgcn_mfma_f32_16x16x32_bf16(afr, bfrk[pf], acc[of][pf], 0, 0, 0); \
    }                                                                          \
    __builtin_amdgcn_s_setprio(0);                                             \
  }

// quarter-slot: issue set S's gathers (tap NN+1) | MFMA kc=S (tap NN) |
// COMB set S -> buf NN+1 | reload dB_S (tap NN+2) | fence
#define QSLOT(NN, S, DB)                                                       \
  {                                                                            \
    if ((NN) < 8){ ISSUE(DB) }                                                 \
    MFMA_Q(NN, S)                                                              \
    if ((NN) < 8){ COMB(DB, LS(S), &A_lds[((NN) + 1) & 1][0]) }                \
    if ((NN) < 7){ DB = descb[(size_t)((NN) + 2) * NHW + M(S)]; }              \
    __builtin_amdgcn_sched_barrier(0);                                         \
  }

#define STEP(NN)                                                               \
  {                                                                            \
    QSLOT(NN, 0, dB0)                                                          \
    QSLOT(NN, 1, dB1)                                                          \
    QSLOT(NN, 2, dB2)                                                          \
    QSLOT(NN, 3, dB3)                                                          \
    __syncthreads();                                                           \
  }

  // prologue: tap 0 -> buf0, one gather set live at a time
  dB0 = descb[M(0)]; dB1 = descb[M(1)]; dB2 = descb[M(2)]; dB3 = descb[M(3)];
  ISSUE(dB0) COMB(dB0, LS(0), &A_lds[0][0])
  __builtin_amdgcn_sched_barrier(0);
  ISSUE(dB1) COMB(dB1, LS(1), &A_lds[0][0])
  __builtin_amdgcn_sched_barrier(0);
  ISSUE(dB2) COMB(dB2, LS(2), &A_lds[0][0])
  __builtin_amdgcn_sched_barrier(0);
  ISSUE(dB3) COMB(dB3, LS(3), &A_lds[0][0])
  dB0 = descb[NHW + M(0)]; dB1 = descb[NHW + M(1)];
  dB2 = descb[NHW + M(2)]; dB3 = descb[NHW + M(3)];
  __syncthreads();

  STEP(0) STEP(1) STEP(2) STEP(3) STEP(4) STEP(5) STEP(6) STEP(7) STEP(8)

  // epilogue: +shift, fast SiLU, store (64 px x 64 oc per wave)
#pragma unroll
  for (int of = 0; of < 4; ++of)
#pragma unroll
    for (int pf = 0; pf < 4; ++pf){
      int pix = pixbase + pf * 16 + (lane & 15);
#pragma unroll
      for (int r = 0; r < 4; ++r){
        int o = ow * 64 + of * 16 + ((lane >> 4) & 3) * 4 + r;
        float v = acc[of][pf][r] + shift[o];
        out[(size_t)(b * 256 + o) * NHW + pix] = fast_silu(v);
      }
    }
#undef M
#undef LS
#undef ISSUE
#undef COMB
#undef MFMA_Q
#undef QSLOT
#undef STEP
}

extern "C" void kernel_launch(void* const* d_in, const int* in_sizes, int n_in,
                              void* d_out, int out_size, void* d_ws, size_t ws_size,
                              hipStream_t stream){
  const float* x       = (const float*)d_in[0];
  const float* w_pconv = (const float*)d_in[1];
  const float* b_pconv = (const float*)d_in[2];
  const float* w_conv  = (const float*)d_in[3];
  const float* gamma   = (const float*)d_in[4];
  const float* beta    = (const float*)d_in[5];
  const float* mean    = (const float*)d_in[6];
  const float* var     = (const float*)d_in[7];
  const float* pn      = (const float*)d_in[8];

  char* ws = (char*)d_ws;
  unsigned short* xt  = (unsigned short*)(ws + 0);           // 13,107,200 B
  unsigned short* xtl = (unsigned short*)(ws + 13107200);    // 13,107,200 B
  uint4* desc         = (uint4*)(ws + 26214400);             //  7,372,800 B
  uint4* wf           = (uint4*)(ws + 33587200);             //    589,824 B
  uint4* wpfH         = (uint4*)(ws + 34177024);             //     73,728 B
  uint4* wpfL         = (uint4*)(ws + 34250752);             //     73,728 B
  float* shift        = (float*)(ws + 34324480);             //      1,024 B
  float* out          = (float*)d_out;

  k_pre<<<981, 256, 0, stream>>>(x, w_conv, w_pconv, gamma, beta, mean, var,
                                 xt, xtl, wf, wpfH, wpfL, shift);
  k_offconv<<<1600, 256, 0, stream>>>(xt, xtl, wpfH, wpfL, b_pconv, pn, desc);
  k_main64<<<800, 256, 0, stream>>>(xt, desc, wf, shift, out);
}

// Round 10
// 114.847 us; speedup vs baseline: 1.6237x; 1.1225x over previous
//
#include <hip/hip_runtime.h>
#include <hip/hip_bf16.h>

// LDConv (deformable sampling + (N,1) conv + BN + SiLU) for MI355X.
//
// Round-23 = BYTE-EXACT REVERT to the proven Round-15 fused kernel
// (benched 114.56us total / ~109us k_fused, absmax 0.0625, PASSED).
//  - R22 post-mortem: single-bf16 offset path FAILED correctness
//    (absmax 1.09 vs 0.27). The linearized error budget (~3e-3) can't
//    produce 1.09 -> either tail amplification through the coherent
//    128-ch sums or a latent bug; either way: the double-bf16 offset
//    path (xt/xtl + 4-term MFMA) is load-bearing. Restored verbatim.
//  - Session model (9 rounds of evidence): total ~= max(L2 stream of
//    ~2.1 GB at the TRUE ~17-19 TB/s ceiling, generations x block
//    latency). R15 is balanced on both axes; schedule-only (R14/17/19),
//    scatter (R16), tile-growth with duplicated wf (R18), concurrency-
//    losing byte cuts (R21), and decomposition (R20) all confirmed the
//    model but did not beat R15. Remaining untried lever: 64-px fused
//    tile with NON-duplicated wf (8 waves x 32-oc slices) — not
//    attempted here to guarantee a green result after R22's failure.
// Carried: fused offset conv -> descL in LDS, XCD swizzle, XOR-swizzled
// 16KB dbuf A_lds, BN folded into wf, fast SiLU, setprio, (256,4).

typedef __attribute__((ext_vector_type(8))) short bf16x8;
typedef __attribute__((ext_vector_type(4))) float f32x4;
typedef __attribute__((ext_vector_type(2))) float f32x2;
typedef __attribute__((ext_vector_type(4))) unsigned int u32x4;

#define NHW 6400
#define NPIX 80

__device__ __forceinline__ unsigned short f2bf(float f){
  __hip_bfloat16 h = __float2bfloat16(f);
  unsigned short u; __builtin_memcpy(&u, &h, 2); return u;
}
__device__ __forceinline__ f32x2 bfp2f(unsigned int u){
  union { unsigned int i; float f; } a, b;
  a.i = u << 16; b.i = u & 0xffff0000u;
  f32x2 r; r.x = a.f; r.y = b.f; return r;
}
__device__ __forceinline__ unsigned pk_bf16(float a, float b){
  unsigned r;
  asm("v_cvt_pk_bf16_f32 %0, %1, %2" : "=v"(r) : "v"(a), "v"(b));
  return r;
}
__device__ __forceinline__ void splitbf(float v, unsigned short& hi, unsigned short& lo){
  hi = f2bf(v);
  union { unsigned int i; float f; } h; h.i = (unsigned)hi << 16;
  lo = f2bf(v - h.f);
}
__device__ __forceinline__ float f16u2f(unsigned int u){
  unsigned short s = (unsigned short)u; _Float16 h;
  __builtin_memcpy(&h, &s, 2); return (float)h;
}
__device__ __forceinline__ unsigned short f2f16u(float f){
  _Float16 h = (_Float16)f; unsigned short s;
  __builtin_memcpy(&s, &h, 2); return s;
}
__device__ __forceinline__ float fast_silu(float v){
  float e, r;
  asm("v_exp_f32 %0, %1" : "=v"(e) : "v"(v * -1.44269504088896f)); // exp(-v)
  asm("v_rcp_f32 %0, %1" : "=v"(r) : "v"(1.0f + e));
  return v * r;
}

// ---------------- merged: transpose (blk<800) + weight prep ----------------
__global__ __launch_bounds__(256) void k_pre(const float* __restrict__ x,
                                             const float* __restrict__ w_conv,
                                             const float* __restrict__ w_pconv,
                                             const float* __restrict__ gamma,
                                             const float* __restrict__ beta,
                                             const float* __restrict__ mean,
                                             const float* __restrict__ var,
                                             unsigned short* __restrict__ xt,
                                             unsigned short* __restrict__ xtl,
                                             uint4* __restrict__ wf,
                                             uint4* __restrict__ wpfH,
                                             uint4* __restrict__ wpfL,
                                             float* __restrict__ shift){
  __shared__ unsigned short tileH[64 * 132];
  __shared__ unsigned short tileL[64 * 132];
  int blk = blockIdx.x; int t = threadIdx.x;
  if (blk < 800){
    int b = blk / 100; int pixbase = (blk % 100) * 64;
    int lane = t & 63; int cg = t >> 6;
    for (int ci = 0; ci < 32; ++ci){
      int c = cg * 32 + ci;
      float v = x[(b * 128 + c) * NHW + pixbase + lane];
      unsigned short hi, lo; splitbf(v, hi, lo);
      tileH[lane * 132 + c] = hi;
      tileL[lane * 132 + c] = lo;
    }
    __syncthreads();
    for (int i = 0; i < 8; ++i){
      int slot = t + i * 256; int m = slot >> 5; int c = (slot & 31) * 4;
      uint2 vH = *reinterpret_cast<const uint2*>(&tileH[m * 132 + c]);
      uint2 vL = *reinterpret_cast<const uint2*>(&tileL[m * 132 + c]);
      *reinterpret_cast<uint2*>(xt  + (b * NHW + pixbase + m) * 128 + c) = vH;
      *reinterpret_cast<uint2*>(xtl + (b * NHW + pixbase + m) * 128 + c) = vL;
    }
    return;
  }
  int pblk = blk - 800;
  if (pblk < 144){
    int id = pblk * 256 + t;
    int lane = id & 63, ofrag = (id >> 6) & 15, kc = (id >> 10) & 3, n = id >> 12;
    int o = ofrag * 16 + (lane & 15), cb = kc * 32 + ((lane >> 4) & 3) * 8;
    float sc = gamma[o] * rsqrtf(var[o] + 1e-5f);       // BN scale folded in
    unsigned short h[8];
    for (int j = 0; j < 8; ++j) h[j] = f2bf(w_conv[(o * 128 + cb + j) * 9 + n] * sc);
    uint4 v;
    v.x = (unsigned)h[0] | ((unsigned)h[1] << 16);
    v.y = (unsigned)h[2] | ((unsigned)h[3] << 16);
    v.z = (unsigned)h[4] | ((unsigned)h[5] << 16);
    v.w = (unsigned)h[6] | ((unsigned)h[7] << 16);
    wf[id] = v;
  } else if (pblk < 180){
    int isLo = (pblk >= 162);
    int id = (pblk - (isLo ? 162 : 144)) * 256 + t;
    int lane = id & 63, ofrag = (id >> 6) & 1, kc = (id >> 7) & 3, tap = id >> 9;
    int o = ofrag * 16 + (lane & 15), cb = kc * 32 + ((lane >> 4) & 3) * 8;
    unsigned short h[8];
    for (int j = 0; j < 8; ++j){
      unsigned short hi = 0, lo = 0;
      if (o < 18) splitbf(w_pconv[(o * 128 + cb + j) * 9 + tap], hi, lo);
      h[j] = isLo ? lo : hi;
    }
    uint4 v;
    v.x = (unsigned)h[0] | ((unsigned)h[1] << 16);
    v.y = (unsigned)h[2] | ((unsigned)h[3] << 16);
    v.z = (unsigned)h[4] | ((unsigned)h[5] << 16);
    v.w = (unsigned)h[6] | ((unsigned)h[7] << 16);
    if (isLo) wpfL[id] = v; else wpfH[id] = v;
  } else {
    float sc = gamma[t] * rsqrtf(var[t] + 1e-5f);
    shift[t] = beta[t] - mean[t] * sc;
  }
}

// ---------------- fused: offset conv -> descL (LDS) -> gather GEMM + BN + SiLU ----------------
// Phase 1 (== k_offconv body): 3x3 offset conv via dbl-bf16 MFMA, descriptor
// build into descL[9*32] in LDS (global desc round-trip eliminated).
// Phase 2 (== k_main body): depth gather pipeline + MFMA GEMM.
// LDS map (24576 B): [0,17408) BtileH/L  | [17408,19968) off_lds
//                    [0,16384)  A_lds[2] (phase 2, after barrier)
//                    [19968,24576) descL (persists across phases)
__global__ __launch_bounds__(256, 4) void k_fused(const unsigned short* __restrict__ xt,
                                                  const unsigned short* __restrict__ xtl,
                                                  const uint4* __restrict__ wpfH,
                                                  const uint4* __restrict__ wpfL,
                                                  const float* __restrict__ bpc,
                                                  const float* __restrict__ pn,
                                                  const uint4* __restrict__ wf,
                                                  const float* __restrict__ shift,
                                                  float* __restrict__ out){
  int bid = blockIdx.x;
  int blk = (bid & 7) * 200 + (bid >> 3);          // XCD swizzle (1600 % 8 == 0)
  int b = blk / 200; int pixbase = (blk % 200) * 32;
  int t = threadIdx.x; int lane = t & 63;

  __shared__ alignas(16) char smem[24576];
  short* BtileH  = (short*)(smem);                 // 32*136*2 = 8704 B
  short* BtileL  = (short*)(smem + 8704);          // 8704 B
  float* off_lds = (float*)(smem + 17408);         // 32*20*4 = 2560 B
  uint4* descL   = (uint4*)(smem + 19968);         // 9*32*16 = 4608 B

  // ======================= phase 1: offset conv =======================
  {
    int wv = t >> 6; int og = wv & 1; int pf = wv >> 1;
    f32x4 acc = (f32x4){0.f, 0.f, 0.f, 0.f};
    const unsigned short* xbH = xt  + (size_t)b * NHW * 128;
    const unsigned short* xbL = xtl + (size_t)b * NHW * 128;

    int m_i[4], c_i[4], h_i[4], w_i[4];
#pragma unroll
    for (int i = 0; i < 4; ++i){
      int slot = t + i * 256;
      m_i[i] = slot >> 5; c_i[i] = (slot & 31) * 4;
      int p = pixbase + m_i[i];
      h_i[i] = p / NPIX; w_i[i] = p % NPIX;
    }

    uint2 rH[4], rL[4];

#define LOADTAP(DH, DW)                                                        \
  _Pragma("unroll")                                                            \
  for (int i = 0; i < 4; ++i){                                                 \
    int h2 = h_i[i] + (DH), w2 = w_i[i] + (DW);                                \
    uint2 vH; vH.x = 0u; vH.y = 0u;                                            \
    uint2 vL; vL.x = 0u; vL.y = 0u;                                            \
    if ((unsigned)h2 < NPIX && (unsigned)w2 < NPIX){                           \
      int off = (h2 * NPIX + w2) * 128 + c_i[i];                               \
      vH = *reinterpret_cast<const uint2*>(xbH + off);                         \
      vL = *reinterpret_cast<const uint2*>(xbL + off);                         \
    }                                                                          \
    rH[i] = vH; rL[i] = vL;                                                    \
  }

#define WRITETILE()                                                            \
  _Pragma("unroll")                                                            \
  for (int i = 0; i < 4; ++i){                                                 \
    *reinterpret_cast<uint2*>(&BtileH[m_i[i] * 136 + c_i[i]]) = rH[i];         \
    *reinterpret_cast<uint2*>(&BtileL[m_i[i] * 136 + c_i[i]]) = rL[i];         \
  }

    LOADTAP(-1, -1)
    WRITETILE()
    __syncthreads();

#pragma unroll 1
    for (int tap = 0; tap < 9; ++tap){
      if (tap < 8){
        int dh2 = (tap + 1) / 3 - 1, dw2 = (tap + 1) % 3 - 1;
        LOADTAP(dh2, dw2)
      }
#pragma unroll
      for (int kc = 0; kc < 4; ++kc){
        int boff = (pf * 16 + (lane & 15)) * 136 + kc * 32 + ((lane >> 4) & 3) * 8;
        bf16x8 bH = *reinterpret_cast<const bf16x8*>(&BtileH[boff]);
        bf16x8 bL = *reinterpret_cast<const bf16x8*>(&BtileL[boff]);
        int widx = ((tap * 4 + kc) * 2 + og) * 64 + lane;
        bf16x8 aH = *reinterpret_cast<const bf16x8*>(&wpfH[widx]);
        bf16x8 aL = *reinterpret_cast<const bf16x8*>(&wpfL[widx]);
        acc = __builtin_amdgcn_mfma_f32_16x16x32_bf16(aH, bH, acc, 0, 0, 0);
        acc = __builtin_amdgcn_mfma_f32_16x16x32_bf16(aH, bL, acc, 0, 0, 0);
        acc = __builtin_amdgcn_mfma_f32_16x16x32_bf16(aL, bH, acc, 0, 0, 0);
        acc = __builtin_amdgcn_mfma_f32_16x16x32_bf16(aL, bL, acc, 0, 0, 0);
      }
      __syncthreads();
      if (tap < 8){
        WRITETILE()
        __syncthreads();
      }
    }

    int pl = pf * 16 + (lane & 15);
#pragma unroll
    for (int r = 0; r < 4; ++r){
      int o = og * 16 + ((lane >> 4) & 3) * 4 + r;
      if (o < 18) off_lds[pl * 20 + o] = acc[r] + bpc[o];
    }
    __syncthreads();

    for (int item = t; item < 288; item += 256){
      int m = item / 9, n = item % 9;
      int p = pixbase + m; int h = p / NPIX, w = p % NPIX;
      float px = (float)h + pn[n]     + off_lds[m * 20 + n];
      float py = (float)w + pn[9 + n] + off_lds[m * 20 + 9 + n];
      float flx = floorf(px), fly = floorf(py);
      float qltx = fminf(fmaxf(flx, 0.f), 79.f);
      float qrbx = fminf(fmaxf(flx + 1.f, 0.f), 79.f);
      float qlty = fminf(fmaxf(fly, 0.f), 79.f);
      float qrby = fminf(fmaxf(fly + 1.f, 0.f), 79.f);
      float pcx = fminf(fmaxf(px, 0.f), 79.f);
      float pcy = fminf(fmaxf(py, 0.f), 79.f);
      float dxl = 1.f + (qltx - pcx), dxr = 1.f - (qrbx - pcx);
      float dyl = 1.f + (qlty - pcy), dyr = 1.f - (qrby - pcy);
      unsigned ix_l = (unsigned)(int)qltx, ix_r = (unsigned)(int)qrbx;
      unsigned iy_l = (unsigned)(int)qlty, iy_r = (unsigned)(int)qrby;
      uint4 d;
      d.x = (ix_l * NPIX + iy_l) | ((ix_r * NPIX + iy_r) << 16);
      d.y = (ix_l * NPIX + iy_r) | ((ix_r * NPIX + iy_l) << 16);
      d.z = (unsigned)f2f16u(dxl * dyl) | ((unsigned)f2f16u(dxr * dyr) << 16);
      d.w = (unsigned)f2f16u(dxl * dyr) | ((unsigned)f2f16u(dxr * dyl) << 16);
      descL[n * 32 + m] = d;
    }
#undef LOADTAP
#undef WRITETILE
  }
  __syncthreads();                 // descL visible; Btile region dead
  __builtin_amdgcn_sched_barrier(0);

  // ======================= phase 2: gather GEMM =======================
  {
    int ow = t >> 6;
    char* A_lds0 = smem;                 // A_lds[buf] = smem + buf*8192
    const char* xb = (const char*)(xt + (size_t)b * NHW * 128);

    int m0 = t >> 4;            // row 0..15
    int m1 = m0 + 16;           // row 16..31
    int cb = (t & 15) * 16;     // byte col 0..240
    int ls0 = m0 * 256 + (cb ^ ((m0 & 7) << 4));
    int ls1 = m1 * 256 + (cb ^ ((m1 & 7) << 4));

    f32x4 acc[4][2];
#pragma unroll
    for (int of = 0; of < 4; ++of)
#pragma unroll
      for (int pf = 0; pf < 2; ++pf)
        acc[of][pf] = (f32x4){0.f, 0.f, 0.f, 0.f};

    u32x4 GX[4], GY[4];          // serialized liveness (never both live)
    uint2 zwX, zwY;
    uint4 dB0, dB1;

#define DLD(N, M) descL[(N) * 32 + (M)]

#define ISSUE_X()                                                              \
  {                                                                            \
    zwX.x = dB0.z; zwX.y = dB0.w;                                              \
    GX[0] = *reinterpret_cast<const u32x4*>(xb + (dB0.x & 0xffffu) * 256u + (unsigned)cb); \
    GX[1] = *reinterpret_cast<const u32x4*>(xb + (dB0.x >> 16)     * 256u + (unsigned)cb); \
    GX[2] = *reinterpret_cast<const u32x4*>(xb + (dB0.y & 0xffffu) * 256u + (unsigned)cb); \
    GX[3] = *reinterpret_cast<const u32x4*>(xb + (dB0.y >> 16)     * 256u + (unsigned)cb); \
  }

#define ISSUE_Y()                                                              \
  {                                                                            \
    zwY.x = dB1.z; zwY.y = dB1.w;                                              \
    GY[0] = *reinterpret_cast<const u32x4*>(xb + (dB1.x & 0xffffu) * 256u + (unsigned)cb); \
    GY[1] = *reinterpret_cast<const u32x4*>(xb + (dB1.x >> 16)     * 256u + (unsigned)cb); \
    GY[2] = *reinterpret_cast<const u32x4*>(xb + (dB1.y & 0xffffu) * 256u + (unsigned)cb); \
    GY[3] = *reinterpret_cast<const u32x4*>(xb + (dB1.y >> 16)     * 256u + (unsigned)cb); \
  }

#define COMB(G, ZW, LSO, WB)                                                   \
  {                                                                            \
    float w0 = f16u2f(ZW.x & 0xffffu), w1 = f16u2f(ZW.x >> 16);                \
    float w2 = f16u2f(ZW.y & 0xffffu), w3 = f16u2f(ZW.y >> 16);                \
    u32x4 pk;                                                                  \
    _Pragma("unroll")                                                          \
    for (int j = 0; j < 4; ++j){                                               \
      f32x2 a = w0 * bfp2f(G[0][j]) + w1 * bfp2f(G[1][j])                      \
              + w2 * bfp2f(G[2][j]) + w3 * bfp2f(G[3][j]);                     \
      pk[j] = pk_bf16(a.x, a.y);                                               \
    }                                                                          \
    *reinterpret_cast<u32x4*>((WB) + (LSO)) = pk;                              \
  }

#define MFMA_HALF(NN, KCA, KCB)                                                \
  {                                                                            \
    const char* ab = A_lds0 + ((NN) & 1) * 8192;                               \
    __builtin_amdgcn_s_setprio(1);                                             \
    _Pragma("unroll")                                                          \
    for (int kc = (KCA); kc <= (KCB); ++kc){                                   \
      bf16x8 bfrk[2];                                                          \
      _Pragma("unroll")                                                        \
      for (int pf = 0; pf < 2; ++pf){                                          \
        int row = pf * 16 + (lane & 15);                                       \
        bfrk[pf] = *reinterpret_cast<const bf16x8*>(                           \
            ab + row * 256 + ((kc * 64 + ((lane >> 4) & 3) * 16) ^ ((row & 7) << 4))); \
      }                                                                        \
      _Pragma("unroll")                                                        \
      for (int of = 0; of < 4; ++of){                                          \
        bf16x8 afr = *reinterpret_cast<const bf16x8*>(                         \
            &wf[((((NN) * 4 + kc) * 16) + ow * 4 + of) * 64 + lane]);          \
        _Pragma("unroll")                                                      \
        for (int pf = 0; pf < 2; ++pf)                                         \
          acc[of][pf] = __builtin_amdgcn_mfma_f32_16x16x32_bf16(afr, bfrk[pf], acc[of][pf], 0, 0, 0); \
      }                                                                        \
    }                                                                          \
    __builtin_amdgcn_s_setprio(0);                                             \
  }

// STEP(NN): issue X(data NN+1) | descL0(NN+2) | MFMA kc0-1 | COMB_X (GX dies)
//           | [sched fence] | issue Y(NN+1) | descL1(NN+2) | MFMA kc2-3
//           | COMB_Y | barrier.
#define STEP(NN)                                                               \
  {                                                                            \
    if ((NN) < 8){ ISSUE_X() }                                                 \
    if ((NN) < 7){ dB0 = DLD((NN) + 2, m0); }                                  \
    MFMA_HALF(NN, 0, 1)                                                        \
    if ((NN) < 8){                                                             \
      COMB(GX, zwX, ls0, A_lds0 + (((NN) + 1) & 1) * 8192)                     \
      __builtin_amdgcn_sched_barrier(0);                                       \
      ISSUE_Y()                                                                \
    }                                                                          \
    if ((NN) < 7){ dB1 = DLD((NN) + 2, m1); }                                  \
    MFMA_HALF(NN, 2, 3)                                                        \
    if ((NN) < 8){                                                             \
      COMB(GY, zwY, ls1, A_lds0 + (((NN) + 1) & 1) * 8192)                     \
    }                                                                          \
    __syncthreads();                                                           \
  }

    // prologue: data 0 -> buf0, one gather set live at a time
    dB0 = DLD(0, m0); dB1 = DLD(0, m1);
    ISSUE_X()
    COMB(GX, zwX, ls0, A_lds0)
    __builtin_amdgcn_sched_barrier(0);
    ISSUE_Y()
    COMB(GY, zwY, ls1, A_lds0)
    dB0 = DLD(1, m0); dB1 = DLD(1, m1);
    __syncthreads();

    STEP(0) STEP(1) STEP(2) STEP(3) STEP(4) STEP(5) STEP(6) STEP(7) STEP(8)

    // epilogue: +shift, fast SiLU, store
#pragma unroll
    for (int of = 0; of < 4; ++of)
#pragma unroll
      for (int pf = 0; pf < 2; ++pf){
        int pix = pixbase + pf * 16 + (lane & 15);
#pragma unroll
        for (int r = 0; r < 4; ++r){
          int o = ow * 64 + of * 16 + ((lane >> 4) & 3) * 4 + r;
          float v = acc[of][pf][r] + shift[o];
          out[(size_t)(b * 256 + o) * NHW + pix] = fast_silu(v);
        }
      }
#undef DLD
#undef ISSUE_X
#undef ISSUE_Y
#undef COMB
#undef MFMA_HALF
#undef STEP
  }
}

extern "C" void kernel_launch(void* const* d_in, const int* in_sizes, int n_in,
                              void* d_out, int out_size, void* d_ws, size_t ws_size,
                              hipStream_t stream){
  const float* x       = (const float*)d_in[0];
  const float* w_pconv = (const float*)d_in[1];
  const float* b_pconv = (const float*)d_in[2];
  const float* w_conv  = (const float*)d_in[3];
  const float* gamma   = (const float*)d_in[4];
  const float* beta    = (const float*)d_in[5];
  const float* mean    = (const float*)d_in[6];
  const float* var     = (const float*)d_in[7];
  const float* pn      = (const float*)d_in[8];

  char* ws = (char*)d_ws;
  unsigned short* xt  = (unsigned short*)(ws + 0);           // 13,107,200 B
  unsigned short* xtl = (unsigned short*)(ws + 13107200);    // 13,107,200 B
  // (desc region [26214400, 33587200) unused — kept for layout stability)
  uint4* wf           = (uint4*)(ws + 33587200);             //    589,824 B
  uint4* wpfH         = (uint4*)(ws + 34177024);             //     73,728 B
  uint4* wpfL         = (uint4*)(ws + 34250752);             //     73,728 B
  float* shift        = (float*)(ws + 34324480);             //      1,024 B
  float* out          = (float*)d_out;

  k_pre<<<981, 256, 0, stream>>>(x, w_conv, w_pconv, gamma, beta, mean, var,
                                 xt, xtl, wf, wpfH, wpfL, shift);
  k_fused<<<1600, 256, 0, stream>>>(xt, xtl, wpfH, wpfL, b_pconv, pn, wf, shift, out);
}